// Round 25
// baseline (97.410 us; speedup 1.0000x reference)
//
#include <hip/hip_runtime.h>
#include <hip/hip_bf16.h>
#include <math.h>

#define B 4
#define L 1024
#define D 256
#define H 8
#define HD 64

// workspace layout (float offsets)
#define KB_OFF  1048576                // Q bf16 [0, KB_OFF) floats
#define VR_OFF  2097152                // K bf16 [KB_OFF, VR_OFF); vr fp32 here
#define TP2_OFF (VR_OFF + 32768)       // Tpart2 fp32 [hb][qt 32][dt 32][64] (8 MB)
#define XP_OFF  (TP2_OFF + 2097152)    // xpe bf16 [4096][256]
#define WT_OFF  (XP_OFF + 524288)      // WT bf16 [1024][256]
// total floats: WT_OFF + 131072 = 4882432 (~19.5 MB)

typedef short short8 __attribute__((ext_vector_type(8)));
typedef float f32x16 __attribute__((ext_vector_type(16)));

__device__ __forceinline__ unsigned short f2bf(float f) {
  __hip_bfloat16 h = __float2bfloat16(f);
  return *reinterpret_cast<unsigned short*>(&h);
}

// ---------------------------------------------------------------------------
// prep_wx: Blocks 0..31: WT transpose. Blocks 32..543: XP = bf16(x+pe)
//          (float4 loads, ushort4 stores); vr = sigmoid(x@Wv) reversed.
// ---------------------------------------------------------------------------
__global__ __launch_bounds__(256) void prep_wx_kernel(
    const float* __restrict__ x, const float* __restrict__ Wq,
    const float* __restrict__ Wk, const float* __restrict__ Wv,
    const float* __restrict__ pe, float* __restrict__ ws)
{
  const int tid = threadIdx.x;
  if (blockIdx.x < 32) {
    __shared__ float lds[32][257];
    const int c0 = blockIdx.x * 32;
    const float* W = (c0 < 512) ? Wq : Wk;
    const int cc = c0 & 511;
    const int c = tid & 31, dd = tid >> 5;
    for (int d0 = 0; d0 < 256; d0 += 8)
      lds[c][d0 + dd] = W[(d0 + dd) * 512 + cc + c];
    __syncthreads();
    __hip_bfloat16* WT = (__hip_bfloat16*)(ws + WT_OFF);
    for (int cl = 0; cl < 32; ++cl)
      WT[(c0 + cl) * 256 + tid] = __float2bfloat16(lds[cl][tid]);
    return;
  }

  __shared__ float xs[8][257];
  const int r0 = (blockIdx.x - 32) * 8;
  __hip_bfloat16* XP = (__hip_bfloat16*)(ws + XP_OFF);
#pragma unroll
  for (int u = 0; u < 2; ++u) {        // 512 float4 units = 8 rows x 64
    int idx = (u << 8) + tid;
    int row = idx >> 6, c4 = idx & 63;
    int gr = r0 + row, l = gr & 1023;
    float4 xv = ((const float4*)(x + (size_t)gr * 256))[c4];
    float4 pv = ((const float4*)(pe + (size_t)l * 256))[c4];
    int c = c4 << 2;
    xs[row][c] = xv.x; xs[row][c + 1] = xv.y;
    xs[row][c + 2] = xv.z; xs[row][c + 3] = xv.w;
    ushort4 pk;
    pk.x = f2bf(xv.x + pv.x); pk.y = f2bf(xv.y + pv.y);
    pk.z = f2bf(xv.z + pv.z); pk.w = f2bf(xv.w + pv.w);
    *(ushort4*)(XP + (size_t)gr * 256 + c) = pk;
  }
  __syncthreads();
  {
    int rr = tid >> 5, h = (tid >> 2) & 7, t4 = tid & 3;
    float acc = 0.f;
    const int d0 = t4 << 6;
#pragma unroll 16
    for (int d = 0; d < 64; ++d) acc += xs[rr][d0 + d] * Wv[(d0 + d) * 8 + h];
    acc += __shfl_down(acc, 1, 4);
    acc += __shfl_down(acc, 2, 4);
    if (t4 == 0) {
      float v = 1.f / (1.f + __expf(-acc));
      int gr = r0 + rr;
      int b = gr >> 10, l = gr & 1023;
      ws[VR_OFF + (h * 4 + b) * 1024 + (1023 - l)] = v;
    }
  }
}

// ---------------------------------------------------------------------------
// qkgemm (REVERTED to r23-proven): 32x64 tile/wave, 4 chains of 8 (K-split),
// grid 512 (2048 waves). B-frag shared by 2 col-chains -> min load traffic.
// ---------------------------------------------------------------------------
__global__ __launch_bounds__(256) void qkgemm_kernel(float* __restrict__ ws,
    const float* __restrict__ bq, const float* __restrict__ bk)
{
  const int tid = threadIdx.x;
  const int w = tid >> 6, lane = tid & 63;
  const int wid = blockIdx.x * 4 + w;
  const int lt = wid & 127;
  const int cp = wid >> 7;           // 0..15 (0..7 -> Q, 8..15 -> K)

  const __hip_bfloat16* XP = (const __hip_bfloat16*)(ws + XP_OFF);
  const __hip_bfloat16* WT = (const __hip_bfloat16*)(ws + WT_OFF);

  const int ln = (lt << 5) + (lane & 31);
  const int dlo = (lane >> 5) << 3;
  const int ca = (cp << 6) + (lane & 31);
  const __hip_bfloat16* xr = XP + ln * 256 + dlo;
  const __hip_bfloat16* ar = WT + ca * 256 + dlo;
  const __hip_bfloat16* br = ar + (32 * 256);

  f32x16 a0 = {0.f,0.f,0.f,0.f,0.f,0.f,0.f,0.f,0.f,0.f,0.f,0.f,0.f,0.f,0.f,0.f};
  f32x16 a1 = {0.f,0.f,0.f,0.f,0.f,0.f,0.f,0.f,0.f,0.f,0.f,0.f,0.f,0.f,0.f,0.f};
  f32x16 b0 = {0.f,0.f,0.f,0.f,0.f,0.f,0.f,0.f,0.f,0.f,0.f,0.f,0.f,0.f,0.f,0.f};
  f32x16 b1 = {0.f,0.f,0.f,0.f,0.f,0.f,0.f,0.f,0.f,0.f,0.f,0.f,0.f,0.f,0.f,0.f};
#pragma unroll
  for (int k = 0; k < 8; ++k) {
    short8 bfA = *(const short8*)(xr + k * 16);
    short8 bfB = *(const short8*)(xr + (k + 8) * 16);
    short8 afa0 = *(const short8*)(ar + k * 16);
    short8 afa1 = *(const short8*)(ar + (k + 8) * 16);
    short8 afb0 = *(const short8*)(br + k * 16);
    short8 afb1 = *(const short8*)(br + (k + 8) * 16);
    a0 = __builtin_amdgcn_mfma_f32_32x32x16_bf16(afa0, bfA, a0, 0, 0, 0);
    a1 = __builtin_amdgcn_mfma_f32_32x32x16_bf16(afa1, bfB, a1, 0, 0, 0);
    b0 = __builtin_amdgcn_mfma_f32_32x32x16_bf16(afb0, bfA, b0, 0, 0, 0);
    b1 = __builtin_amdgcn_mfma_f32_32x32x16_bf16(afb1, bfB, b1, 0, 0, 0);
  }
  f32x16 acca, accb;
#pragma unroll
  for (int r = 0; r < 16; ++r) { acca[r] = a0[r] + a1[r]; accb[r] = b0[r] + b1[r]; }

  const int b = ln >> 10, l = ln & 1023;
  const int hq = cp & 7;
  const int hi4 = (lane >> 5) << 2;
  const float* bias = (cp < 8) ? bq : bk;
  const int cbase = hq << 6;
  __hip_bfloat16* base = (__hip_bfloat16*)ws + ((cp < 8) ? 0 : (size_t)KB_OFF * 2);
  __hip_bfloat16* dst = base + ((((size_t)(hq * 4 + b) << 10) + l) << 6);

#pragma unroll
  for (int q = 0; q < 4; ++q) {
    int hd0 = (q << 3) + hi4;
    float4 bv = *(const float4*)(bias + cbase + hd0);
    ushort4 pk;
    pk.x = f2bf(acca[4 * q + 0] + bv.x);
    pk.y = f2bf(acca[4 * q + 1] + bv.y);
    pk.z = f2bf(acca[4 * q + 2] + bv.z);
    pk.w = f2bf(acca[4 * q + 3] + bv.w);
    *(ushort4*)(dst + hd0) = pk;

    int hd1 = hd0 + 32;
    float4 bw = *(const float4*)(bias + cbase + hd1);
    ushort4 pk2;
    pk2.x = f2bf(accb[4 * q + 0] + bw.x);
    pk2.y = f2bf(accb[4 * q + 1] + bw.y);
    pk2.z = f2bf(accb[4 * q + 2] + bw.z);
    pk2.w = f2bf(accb[4 * q + 3] + bw.w);
    *(ushort4*)(dst + hd1) = pk2;
  }
}

// ---------------------------------------------------------------------------
// attn: r21 structure + T14 async-STAGE pipeline in phase 1 (load chunk c+1
// to regs before computing chunk c; LDS-write after barrier).
// ---------------------------------------------------------------------------
__global__ __launch_bounds__(256) void attn_kernel(float* __restrict__ ws)
{
  __shared__ __hip_bfloat16 Ks[256 * 64];   // 32 KB chunk buffer (swizzled)
  __shared__ float smerge[4][32];
  const int tid = threadIdx.x;
  const int w = tid >> 6, lane = tid & 63;
  const int i = blockIdx.x;
  const int hb = i & 31;
  const int j = i >> 5;
  const int qt = (j & 8) ? ((j < 16) ? 23 - j : 55 - j) : j;

  const __hip_bfloat16* Qb = (const __hip_bfloat16*)ws + ((size_t)hb << 16);
  const __hip_bfloat16* Kb = (const __hip_bfloat16*)(ws + KB_OFF) + ((size_t)hb << 16);
  const float* __restrict__ vr = ws + VR_OFF + (hb << 10);

  const int qrow = (qt << 5) + (lane & 31);
  const int dlo = (lane >> 5) << 3;
  const int coff = (lane >> 5) << 2;

  const __hip_bfloat16* qr = Qb + (qrow << 6) + dlo;
  short8 qf0 = *(const short8*)(qr);
  short8 qf1 = *(const short8*)(qr + 16);
  short8 qf2 = *(const short8*)(qr + 32);
  short8 qf3 = *(const short8*)(qr + 48);

  // split staging: load chunk c to regs / write regs to swizzled LDS
#define SLOAD(c, v)                                                           \
  {                                                                           \
    const float4* src_ = (const float4*)Kb + ((c) << 11);                     \
    _Pragma("unroll")                                                         \
    for (int u = 0; u < 8; ++u) v[u] = src_[(u << 8) + tid];                  \
  }
#define SWRITE(v)                                                             \
  {                                                                           \
    _Pragma("unroll")                                                         \
    for (int u = 0; u < 8; ++u) {                                             \
      int idx_ = (u << 8) + tid;                                              \
      int row_ = idx_ >> 3;                                                   \
      int colb_ = (idx_ & 7) << 4;                                            \
      *(float4*)((char*)Ks + row_ * 128 + (colb_ ^ ((row_ & 7) << 4))) = v[u];\
    }                                                                         \
  }

#define LDK(tl, kf)                                                           \
  {                                                                           \
    int row_ = ((tl) << 5) + (lane & 31);                                     \
    int sw_ = (row_ & 7) << 4;                                                \
    int cb_ = (lane >> 5) << 4;                                               \
    char* bp_ = (char*)Ks + row_ * 128;                                       \
    kf[0] = *(const short8*)(bp_ + ((cb_) ^ sw_));                            \
    kf[1] = *(const short8*)(bp_ + ((cb_ + 32) ^ sw_));                       \
    kf[2] = *(const short8*)(bp_ + ((cb_ + 64) ^ sw_));                       \
    kf[3] = *(const short8*)(bp_ + ((cb_ + 96) ^ sw_));                       \
  }

  // ---- phase 1: pipelined denominator over 4 chunks ----
  float sp0 = 0.f, sp1 = 0.f, sp2 = 0.f, sp3 = 0.f;
  {
    float4 vcur[8], vnext[8];
    SLOAD(0, vcur);
    SWRITE(vcur);
    __syncthreads();
    for (int c = 0; c < 4; ++c) {
      if (c < 3) SLOAD(c + 1, vnext);       // issue early; hides under compute
      short8 ka[4], kb[4];
      LDK(w, ka);
      LDK(w + 4, kb);
      f32x16 acca = {0.f,0.f,0.f,0.f,0.f,0.f,0.f,0.f,0.f,0.f,0.f,0.f,0.f,0.f,0.f,0.f};
      f32x16 accb = {0.f,0.f,0.f,0.f,0.f,0.f,0.f,0.f,0.f,0.f,0.f,0.f,0.f,0.f,0.f,0.f};
      acca = __builtin_amdgcn_mfma_f32_32x32x16_bf16(ka[0], qf0, acca, 0, 0, 0);
      accb = __builtin_amdgcn_mfma_f32_32x32x16_bf16(kb[0], qf0, accb, 0, 0, 0);
      acca = __builtin_amdgcn_mfma_f32_32x32x16_bf16(ka[1], qf1, acca, 0, 0, 0);
      accb = __builtin_amdgcn_mfma_f32_32x32x16_bf16(kb[1], qf1, accb, 0, 0, 0);
      acca = __builtin_amdgcn_mfma_f32_32x32x16_bf16(ka[2], qf2, acca, 0, 0, 0);
      accb = __builtin_amdgcn_mfma_f32_32x32x16_bf16(kb[2], qf2, accb, 0, 0, 0);
      acca = __builtin_amdgcn_mfma_f32_32x32x16_bf16(ka[3], qf3, acca, 0, 0, 0);
      accb = __builtin_amdgcn_mfma_f32_32x32x16_bf16(kb[3], qf3, accb, 0, 0, 0);
#pragma unroll
      for (int r = 0; r < 16; r += 2) {
        sp0 += __expf(acca[r] * 0.125f);
        sp1 += __expf(acca[r + 1] * 0.125f);
        sp2 += __expf(accb[r] * 0.125f);
        sp3 += __expf(accb[r + 1] * 0.125f);
      }
      __syncthreads();                      // all waves done reading chunk c
      if (c < 3) {
        SWRITE(vnext);
        __syncthreads();                    // chunk c+1 visible
      }
    }
  }
  float s_part = (sp0 + sp1) + (sp2 + sp3);
  s_part += __shfl_xor(s_part, 32);
  if (lane < 32) smerge[w][lane] = s_part;
  __syncthreads();
  const int q = lane & 31;
  const float inv = 1.f / (smerge[0][q] + smerge[1][q] + smerge[2][q] + smerge[3][q]);

#define FLUSH(dt_, acc_)                                                      \
  {                                                                           \
    const int kt_ = qt + (dt_);                                               \
    const float* vb_ = vr + (kt_ << 5) + coff;                                \
    float4 v0_ = *(const float4*)(vb_);                                       \
    float4 v1_ = *(const float4*)(vb_ + 8);                                   \
    float4 v2_ = *(const float4*)(vb_ + 16);                                  \
    float4 v3_ = *(const float4*)(vb_ + 24);                                  \
    float p_[16];                                                             \
    _Pragma("unroll")                                                         \
    for (int r = 0; r < 16; ++r) {                                            \
      float vv_ = (r < 4) ? (&v0_.x)[r] : (r < 8) ? (&v1_.x)[r - 4]           \
                : (r < 12) ? (&v2_.x)[r - 8] : (&v3_.x)[r - 12];              \
      p_[r] = __expf(acc_[r] * 0.125f) * vv_ * inv;                           \
    }                                                                         \
    float accg_ = 0.f;                                                        \
    _Pragma("unroll")                                                         \
    for (int hi = 0; hi < 2; ++hi)                                            \
      _Pragma("unroll")                                                       \
      for (int r = 0; r < 16; ++r) {                                          \
        const int km_ = (hi << 2) + (r & 3) + ((r >> 2) << 3);                \
        int src_ = ((hi << 5) + km_ + 31 - lane) & 63;                        \
        float g_ = __shfl(p_[r], src_);                                       \
        if (km_ <= lane && km_ >= lane - 31) accg_ += g_;                     \
      }                                                                       \
    ws[TP2_OFF + ((size_t)hb << 16) + ((((qt) << 5) + (dt_)) << 6) + lane] = accg_; \
  }

  // ---- phase 2: chunks descending; chunk 3 still resident (from phase 1) ----
  const int c0 = qt >> 3;
  for (int c = 3; c >= c0; --c) {
    if (c != 3) {
      float4 v[8];
      SLOAD(c, v);
      __syncthreads();
      SWRITE(v);
      __syncthreads();
    }
    const int kta = (c << 3) + w;
    const int ktb = kta + 4;
    if (kta >= qt) {
      short8 ka[4], kb[4];
      LDK(w, ka);
      LDK(w + 4, kb);
      f32x16 acca = {0.f,0.f,0.f,0.f,0.f,0.f,0.f,0.f,0.f,0.f,0.f,0.f,0.f,0.f,0.f,0.f};
      f32x16 accb = {0.f,0.f,0.f,0.f,0.f,0.f,0.f,0.f,0.f,0.f,0.f,0.f,0.f,0.f,0.f,0.f};
      acca = __builtin_amdgcn_mfma_f32_32x32x16_bf16(ka[0], qf0, acca, 0, 0, 0);
      accb = __builtin_amdgcn_mfma_f32_32x32x16_bf16(kb[0], qf0, accb, 0, 0, 0);
      acca = __builtin_amdgcn_mfma_f32_32x32x16_bf16(ka[1], qf1, acca, 0, 0, 0);
      accb = __builtin_amdgcn_mfma_f32_32x32x16_bf16(kb[1], qf1, accb, 0, 0, 0);
      acca = __builtin_amdgcn_mfma_f32_32x32x16_bf16(ka[2], qf2, acca, 0, 0, 0);
      accb = __builtin_amdgcn_mfma_f32_32x32x16_bf16(kb[2], qf2, accb, 0, 0, 0);
      acca = __builtin_amdgcn_mfma_f32_32x32x16_bf16(ka[3], qf3, acca, 0, 0, 0);
      accb = __builtin_amdgcn_mfma_f32_32x32x16_bf16(kb[3], qf3, accb, 0, 0, 0);
      FLUSH(kta - qt, acca);
      FLUSH(ktb - qt, accb);
    } else if (ktb >= qt) {
      short8 kb[4];
      LDK(w + 4, kb);
      f32x16 accb = {0.f,0.f,0.f,0.f,0.f,0.f,0.f,0.f,0.f,0.f,0.f,0.f,0.f,0.f,0.f,0.f};
      accb = __builtin_amdgcn_mfma_f32_32x32x16_bf16(kb[0], qf0, accb, 0, 0, 0);
      accb = __builtin_amdgcn_mfma_f32_32x32x16_bf16(kb[1], qf1, accb, 0, 0, 0);
      accb = __builtin_amdgcn_mfma_f32_32x32x16_bf16(kb[2], qf2, accb, 0, 0, 0);
      accb = __builtin_amdgcn_mfma_f32_32x32x16_bf16(kb[3], qf3, accb, 0, 0, 0);
      FLUSH(ktb - qt, accb);
    }
  }
}

// ---------------------------------------------------------------------------
// out (fused): block per (jc, hb) computes T for its 32 j's + 2 halo
// (8 thr each via shfl), stages in LDS, windows, stores.
// Grid 1024 = (jc 32) x (hb 32).
// ---------------------------------------------------------------------------
__global__ __launch_bounds__(256) void out_kernel(const float* __restrict__ ws,
                                                  float* __restrict__ out)
{
  __shared__ float sT[34];
  const int tid = threadIdx.x;
  const int i = blockIdx.x;
  const int hb = i & 31;
  const int jc = i >> 5;
  const int j0 = jc << 5;
  const float* TP = ws + TP2_OFF + ((size_t)hb << 16);

#define TSUM(jj_, t8_, res_)                                                  \
  {                                                                           \
    float acc_ = 0.f;                                                         \
    if ((jj_) >= 0 && (jj_) < 1024) {                                         \
      const int s_ = (jj_) + 31;                                              \
      _Pragma("unroll")                                                       \
      for (int cand = 0; cand < 2; ++cand) {                                  \
        int dt = (s_ >> 5) - cand;                                            \
        if (dt < 0 || dt > 31) continue;                                      \
        int idx = s_ - (dt << 5);                                             \
        int qmax = 31 - dt;                                                   \
        for (int qt = (t8_); qt <= qmax; qt += 8)                             \
          acc_ += TP[(((qt << 5) + dt) << 6) + idx];                          \
      }                                                                       \
    }                                                                         \
    acc_ += __shfl_down(acc_, 4, 8);                                          \
    acc_ += __shfl_down(acc_, 2, 8);                                          \
    acc_ += __shfl_down(acc_, 1, 8);                                          \
    res_ = acc_;                                                              \
  }

  {
    int jloc = tid >> 3, t8 = tid & 7;
    float r;
    TSUM(j0 + jloc - 1, t8, r);
    if (t8 == 0) sT[jloc] = r;
  }
  if (tid < 16) {
    int jx = tid >> 3, t8 = tid & 7;
    float r;
    TSUM(j0 + 31 + jx, t8, r);
    if (t8 == 0) sT[32 + jx] = r;
  }
  __syncthreads();
  if (tid < 32) {
    int j = j0 + tid;
    float cnt = (j == 0 || j == 1023) ? 2.f : 3.f;
    float v = (sT[tid] + sT[tid + 1] + sT[tid + 2]) / cnt;
    int h = hb >> 2, b = hb & 3;
    out[(((b << 10) + j) << 3) + h] = v;
  }
}

extern "C" void kernel_launch(void* const* d_in, const int* in_sizes, int n_in,
                              void* d_out, int out_size, void* d_ws, size_t ws_size,
                              hipStream_t stream)
{
  const float* x  = (const float*)d_in[0];
  const float* Wq = (const float*)d_in[1];
  const float* bq = (const float*)d_in[2];
  const float* Wk = (const float*)d_in[3];
  const float* bk = (const float*)d_in[4];
  const float* Wv = (const float*)d_in[5];
  const float* pe = (const float*)d_in[6];
  float* ws = (float*)d_ws;
  float* out = (float*)d_out;

  prep_wx_kernel<<<dim3(544), dim3(256), 0, stream>>>(x, Wq, Wk, Wv, pe, ws);
  qkgemm_kernel<<<dim3(512), dim3(256), 0, stream>>>(ws, bq, bk);
  attn_kernel<<<dim3(1024), dim3(256), 0, stream>>>(ws);
  out_kernel<<<dim3(1024), dim3(256), 0, stream>>>(ws, out);
}

// Round 26
// 59.231 us; speedup vs baseline: 1.6446x; 1.6446x over previous
//
#include <hip/hip_runtime.h>
#include <hip/hip_bf16.h>
#include <math.h>

#define B 4
#define L 1024
#define D 256
#define H 8
#define HD 64

// workspace layout (float offsets)
#define KB_OFF  1048576                // Q bf16 [0, KB_OFF) floats
#define VR_OFF  2097152                // K bf16 [KB_OFF, VR_OFF); vr fp32 here
#define TP2_OFF (VR_OFF + 32768)       // Tpart2 fp32 [hb][qt 32][dt 32][64] (8 MB)
#define XP_OFF  (TP2_OFF + 2097152)    // xpe bf16 [4096][256]
#define WT_OFF  (XP_OFF + 524288)      // WT bf16 [1024][256]
// total floats: WT_OFF + 131072 = 4882432 (~19.5 MB)

typedef short short8 __attribute__((ext_vector_type(8)));
typedef float f32x16 __attribute__((ext_vector_type(16)));

__device__ __forceinline__ unsigned short f2bf(float f) {
  __hip_bfloat16 h = __float2bfloat16(f);
  return *reinterpret_cast<unsigned short*>(&h);
}

// ---------------------------------------------------------------------------
// prep_wx: Blocks 0..31: WT transpose. Blocks 32..543: XP = bf16(x+pe)
//          (float4 loads, ushort4 stores); vr = sigmoid(x@Wv) reversed.
// ---------------------------------------------------------------------------
__global__ __launch_bounds__(256) void prep_wx_kernel(
    const float* __restrict__ x, const float* __restrict__ Wq,
    const float* __restrict__ Wk, const float* __restrict__ Wv,
    const float* __restrict__ pe, float* __restrict__ ws)
{
  const int tid = threadIdx.x;
  if (blockIdx.x < 32) {
    __shared__ float lds[32][257];
    const int c0 = blockIdx.x * 32;
    const float* W = (c0 < 512) ? Wq : Wk;
    const int cc = c0 & 511;
    const int c = tid & 31, dd = tid >> 5;
    for (int d0 = 0; d0 < 256; d0 += 8)
      lds[c][d0 + dd] = W[(d0 + dd) * 512 + cc + c];
    __syncthreads();
    __hip_bfloat16* WT = (__hip_bfloat16*)(ws + WT_OFF);
    for (int cl = 0; cl < 32; ++cl)
      WT[(c0 + cl) * 256 + tid] = __float2bfloat16(lds[cl][tid]);
    return;
  }

  __shared__ float xs[8][257];
  const int r0 = (blockIdx.x - 32) * 8;
  __hip_bfloat16* XP = (__hip_bfloat16*)(ws + XP_OFF);
#pragma unroll
  for (int u = 0; u < 2; ++u) {        // 512 float4 units = 8 rows x 64
    int idx = (u << 8) + tid;
    int row = idx >> 6, c4 = idx & 63;
    int gr = r0 + row, l = gr & 1023;
    float4 xv = ((const float4*)(x + (size_t)gr * 256))[c4];
    float4 pv = ((const float4*)(pe + (size_t)l * 256))[c4];
    int c = c4 << 2;
    xs[row][c] = xv.x; xs[row][c + 1] = xv.y;
    xs[row][c + 2] = xv.z; xs[row][c + 3] = xv.w;
    ushort4 pk;
    pk.x = f2bf(xv.x + pv.x); pk.y = f2bf(xv.y + pv.y);
    pk.z = f2bf(xv.z + pv.z); pk.w = f2bf(xv.w + pv.w);
    *(ushort4*)(XP + (size_t)gr * 256 + c) = pk;
  }
  __syncthreads();
  {
    int rr = tid >> 5, h = (tid >> 2) & 7, t4 = tid & 3;
    float acc = 0.f;
    const int d0 = t4 << 6;
#pragma unroll 16
    for (int d = 0; d < 64; ++d) acc += xs[rr][d0 + d] * Wv[(d0 + d) * 8 + h];
    acc += __shfl_down(acc, 1, 4);
    acc += __shfl_down(acc, 2, 4);
    if (t4 == 0) {
      float v = 1.f / (1.f + __expf(-acc));
      int gr = r0 + rr;
      int b = gr >> 10, l = gr & 1023;
      ws[VR_OFF + (h * 4 + b) * 1024 + (1023 - l)] = v;
    }
  }
}

// ---------------------------------------------------------------------------
// qkgemm: Q|K = bf16(XP @ [Wq|Wk] + bias) via MFMA; 4 chains of 8 (K-split).
// 32x64 tile/wave, grid 512. B-frag shared by 2 col-chains.
// ---------------------------------------------------------------------------
__global__ __launch_bounds__(256) void qkgemm_kernel(float* __restrict__ ws,
    const float* __restrict__ bq, const float* __restrict__ bk)
{
  const int tid = threadIdx.x;
  const int w = tid >> 6, lane = tid & 63;
  const int wid = blockIdx.x * 4 + w;
  const int lt = wid & 127;
  const int cp = wid >> 7;           // 0..15 (0..7 -> Q, 8..15 -> K)

  const __hip_bfloat16* XP = (const __hip_bfloat16*)(ws + XP_OFF);
  const __hip_bfloat16* WT = (const __hip_bfloat16*)(ws + WT_OFF);

  const int ln = (lt << 5) + (lane & 31);
  const int dlo = (lane >> 5) << 3;
  const int ca = (cp << 6) + (lane & 31);
  const __hip_bfloat16* xr = XP + ln * 256 + dlo;
  const __hip_bfloat16* ar = WT + ca * 256 + dlo;
  const __hip_bfloat16* br = ar + (32 * 256);

  f32x16 a0 = {0.f,0.f,0.f,0.f,0.f,0.f,0.f,0.f,0.f,0.f,0.f,0.f,0.f,0.f,0.f,0.f};
  f32x16 a1 = {0.f,0.f,0.f,0.f,0.f,0.f,0.f,0.f,0.f,0.f,0.f,0.f,0.f,0.f,0.f,0.f};
  f32x16 b0 = {0.f,0.f,0.f,0.f,0.f,0.f,0.f,0.f,0.f,0.f,0.f,0.f,0.f,0.f,0.f,0.f};
  f32x16 b1 = {0.f,0.f,0.f,0.f,0.f,0.f,0.f,0.f,0.f,0.f,0.f,0.f,0.f,0.f,0.f,0.f};
#pragma unroll
  for (int k = 0; k < 8; ++k) {
    short8 bfA = *(const short8*)(xr + k * 16);
    short8 bfB = *(const short8*)(xr + (k + 8) * 16);
    short8 afa0 = *(const short8*)(ar + k * 16);
    short8 afa1 = *(const short8*)(ar + (k + 8) * 16);
    short8 afb0 = *(const short8*)(br + k * 16);
    short8 afb1 = *(const short8*)(br + (k + 8) * 16);
    a0 = __builtin_amdgcn_mfma_f32_32x32x16_bf16(afa0, bfA, a0, 0, 0, 0);
    a1 = __builtin_amdgcn_mfma_f32_32x32x16_bf16(afa1, bfB, a1, 0, 0, 0);
    b0 = __builtin_amdgcn_mfma_f32_32x32x16_bf16(afb0, bfA, b0, 0, 0, 0);
    b1 = __builtin_amdgcn_mfma_f32_32x32x16_bf16(afb1, bfB, b1, 0, 0, 0);
  }
  f32x16 acca, accb;
#pragma unroll
  for (int r = 0; r < 16; ++r) { acca[r] = a0[r] + a1[r]; accb[r] = b0[r] + b1[r]; }

  const int b = ln >> 10, l = ln & 1023;
  const int hq = cp & 7;
  const int hi4 = (lane >> 5) << 2;
  const float* bias = (cp < 8) ? bq : bk;
  const int cbase = hq << 6;
  __hip_bfloat16* base = (__hip_bfloat16*)ws + ((cp < 8) ? 0 : (size_t)KB_OFF * 2);
  __hip_bfloat16* dst = base + ((((size_t)(hq * 4 + b) << 10) + l) << 6);

#pragma unroll
  for (int q = 0; q < 4; ++q) {
    int hd0 = (q << 3) + hi4;
    float4 bv = *(const float4*)(bias + cbase + hd0);
    ushort4 pk;
    pk.x = f2bf(acca[4 * q + 0] + bv.x);
    pk.y = f2bf(acca[4 * q + 1] + bv.y);
    pk.z = f2bf(acca[4 * q + 2] + bv.z);
    pk.w = f2bf(acca[4 * q + 3] + bv.w);
    *(ushort4*)(dst + hd0) = pk;

    int hd1 = hd0 + 32;
    float4 bw = *(const float4*)(bias + cbase + hd1);
    ushort4 pk2;
    pk2.x = f2bf(accb[4 * q + 0] + bw.x);
    pk2.y = f2bf(accb[4 * q + 1] + bw.y);
    pk2.z = f2bf(accb[4 * q + 2] + bw.z);
    pk2.w = f2bf(accb[4 * q + 3] + bw.w);
    *(ushort4*)(dst + hd1) = pk2;
  }
}

// ---------------------------------------------------------------------------
// attn (r21/r23-proven): LDS-staged K (XOR swizzle, direct STAGE8), balanced
// qt, fused 2-phase, shfl gather, direct Tpart2 stores, zero atomics.
// ---------------------------------------------------------------------------
__global__ __launch_bounds__(256) void attn_kernel(float* __restrict__ ws)
{
  __shared__ __hip_bfloat16 Ks[256 * 64];   // 32 KB chunk buffer (swizzled)
  __shared__ float smerge[4][32];
  const int tid = threadIdx.x;
  const int w = tid >> 6, lane = tid & 63;
  const int i = blockIdx.x;
  const int hb = i & 31;
  const int j = i >> 5;
  const int qt = (j & 8) ? ((j < 16) ? 23 - j : 55 - j) : j;

  const __hip_bfloat16* Qb = (const __hip_bfloat16*)ws + ((size_t)hb << 16);
  const __hip_bfloat16* Kb = (const __hip_bfloat16*)(ws + KB_OFF) + ((size_t)hb << 16);
  const float* __restrict__ vr = ws + VR_OFF + (hb << 10);

  const int qrow = (qt << 5) + (lane & 31);
  const int dlo = (lane >> 5) << 3;
  const int coff = (lane >> 5) << 2;

  const __hip_bfloat16* qr = Qb + (qrow << 6) + dlo;
  short8 qf0 = *(const short8*)(qr);
  short8 qf1 = *(const short8*)(qr + 16);
  short8 qf2 = *(const short8*)(qr + 32);
  short8 qf3 = *(const short8*)(qr + 48);

#define STAGE8(c)                                                             \
  {                                                                           \
    const float4* src_ = (const float4*)Kb + ((c) << 11);                     \
    _Pragma("unroll")                                                         \
    for (int u = 0; u < 8; ++u) {                                             \
      int idx_ = (u << 8) + tid;                                              \
      float4 v_ = src_[idx_];                                                 \
      int row_ = idx_ >> 3;                                                   \
      int colb_ = (idx_ & 7) << 4;                                            \
      *(float4*)((char*)Ks + row_ * 128 + (colb_ ^ ((row_ & 7) << 4))) = v_;  \
    }                                                                         \
  }

#define LDK(tl, kf)                                                           \
  {                                                                           \
    int row_ = ((tl) << 5) + (lane & 31);                                     \
    int sw_ = (row_ & 7) << 4;                                                \
    int cb_ = (lane >> 5) << 4;                                               \
    char* bp_ = (char*)Ks + row_ * 128;                                       \
    kf[0] = *(const short8*)(bp_ + ((cb_) ^ sw_));                            \
    kf[1] = *(const short8*)(bp_ + ((cb_ + 32) ^ sw_));                       \
    kf[2] = *(const short8*)(bp_ + ((cb_ + 64) ^ sw_));                       \
    kf[3] = *(const short8*)(bp_ + ((cb_ + 96) ^ sw_));                       \
  }

  float sp0 = 0.f, sp1 = 0.f, sp2 = 0.f, sp3 = 0.f;
  for (int c = 0; c < 4; ++c) {
    if (c) __syncthreads();
    STAGE8(c);
    __syncthreads();
    short8 ka[4], kb[4];
    LDK(w, ka);
    LDK(w + 4, kb);
    f32x16 acca = {0.f,0.f,0.f,0.f,0.f,0.f,0.f,0.f,0.f,0.f,0.f,0.f,0.f,0.f,0.f,0.f};
    f32x16 accb = {0.f,0.f,0.f,0.f,0.f,0.f,0.f,0.f,0.f,0.f,0.f,0.f,0.f,0.f,0.f,0.f};
    acca = __builtin_amdgcn_mfma_f32_32x32x16_bf16(ka[0], qf0, acca, 0, 0, 0);
    accb = __builtin_amdgcn_mfma_f32_32x32x16_bf16(kb[0], qf0, accb, 0, 0, 0);
    acca = __builtin_amdgcn_mfma_f32_32x32x16_bf16(ka[1], qf1, acca, 0, 0, 0);
    accb = __builtin_amdgcn_mfma_f32_32x32x16_bf16(kb[1], qf1, accb, 0, 0, 0);
    acca = __builtin_amdgcn_mfma_f32_32x32x16_bf16(ka[2], qf2, acca, 0, 0, 0);
    accb = __builtin_amdgcn_mfma_f32_32x32x16_bf16(kb[2], qf2, accb, 0, 0, 0);
    acca = __builtin_amdgcn_mfma_f32_32x32x16_bf16(ka[3], qf3, acca, 0, 0, 0);
    accb = __builtin_amdgcn_mfma_f32_32x32x16_bf16(kb[3], qf3, accb, 0, 0, 0);
#pragma unroll
    for (int r = 0; r < 16; r += 2) {
      sp0 += __expf(acca[r] * 0.125f);
      sp1 += __expf(acca[r + 1] * 0.125f);
      sp2 += __expf(accb[r] * 0.125f);
      sp3 += __expf(accb[r + 1] * 0.125f);
    }
  }
  float s_part = (sp0 + sp1) + (sp2 + sp3);
  s_part += __shfl_xor(s_part, 32);
  if (lane < 32) smerge[w][lane] = s_part;
  __syncthreads();
  const int q = lane & 31;
  const float inv = 1.f / (smerge[0][q] + smerge[1][q] + smerge[2][q] + smerge[3][q]);

#define FLUSH(dt_, acc_)                                                      \
  {                                                                           \
    const int kt_ = qt + (dt_);                                               \
    const float* vb_ = vr + (kt_ << 5) + coff;                                \
    float4 v0_ = *(const float4*)(vb_);                                       \
    float4 v1_ = *(const float4*)(vb_ + 8);                                   \
    float4 v2_ = *(const float4*)(vb_ + 16);                                  \
    float4 v3_ = *(const float4*)(vb_ + 24);                                  \
    float p_[16];                                                             \
    _Pragma("unroll")                                                         \
    for (int r = 0; r < 16; ++r) {                                            \
      float vv_ = (r < 4) ? (&v0_.x)[r] : (r < 8) ? (&v1_.x)[r - 4]           \
                : (r < 12) ? (&v2_.x)[r - 8] : (&v3_.x)[r - 12];              \
      p_[r] = __expf(acc_[r] * 0.125f) * vv_ * inv;                           \
    }                                                                         \
    float accg_ = 0.f;                                                        \
    _Pragma("unroll")                                                         \
    for (int hi = 0; hi < 2; ++hi)                                            \
      _Pragma("unroll")                                                       \
      for (int r = 0; r < 16; ++r) {                                          \
        const int km_ = (hi << 2) + (r & 3) + ((r >> 2) << 3);                \
        int src_ = ((hi << 5) + km_ + 31 - lane) & 63;                        \
        float g_ = __shfl(p_[r], src_);                                       \
        if (km_ <= lane && km_ >= lane - 31) accg_ += g_;                     \
      }                                                                       \
    ws[TP2_OFF + ((size_t)hb << 16) + ((((qt) << 5) + (dt_)) << 6) + lane] = accg_; \
  }

  const int c0 = qt >> 3;
  for (int c = 3; c >= c0; --c) {
    if (c != 3) {
      __syncthreads();
      STAGE8(c);
      __syncthreads();
    }
    const int kta = (c << 3) + w;
    const int ktb = kta + 4;
    if (kta >= qt) {
      short8 ka[4], kb[4];
      LDK(w, ka);
      LDK(w + 4, kb);
      f32x16 acca = {0.f,0.f,0.f,0.f,0.f,0.f,0.f,0.f,0.f,0.f,0.f,0.f,0.f,0.f,0.f,0.f};
      f32x16 accb = {0.f,0.f,0.f,0.f,0.f,0.f,0.f,0.f,0.f,0.f,0.f,0.f,0.f,0.f,0.f,0.f};
      acca = __builtin_amdgcn_mfma_f32_32x32x16_bf16(ka[0], qf0, acca, 0, 0, 0);
      accb = __builtin_amdgcn_mfma_f32_32x32x16_bf16(kb[0], qf0, accb, 0, 0, 0);
      acca = __builtin_amdgcn_mfma_f32_32x32x16_bf16(ka[1], qf1, acca, 0, 0, 0);
      accb = __builtin_amdgcn_mfma_f32_32x32x16_bf16(kb[1], qf1, accb, 0, 0, 0);
      acca = __builtin_amdgcn_mfma_f32_32x32x16_bf16(ka[2], qf2, acca, 0, 0, 0);
      accb = __builtin_amdgcn_mfma_f32_32x32x16_bf16(kb[2], qf2, accb, 0, 0, 0);
      acca = __builtin_amdgcn_mfma_f32_32x32x16_bf16(ka[3], qf3, acca, 0, 0, 0);
      accb = __builtin_amdgcn_mfma_f32_32x32x16_bf16(kb[3], qf3, accb, 0, 0, 0);
      FLUSH(kta - qt, acca);
      FLUSH(ktb - qt, accb);
    } else if (ktb >= qt) {
      short8 kb[4];
      LDK(w + 4, kb);
      f32x16 accb = {0.f,0.f,0.f,0.f,0.f,0.f,0.f,0.f,0.f,0.f,0.f,0.f,0.f,0.f,0.f,0.f};
      accb = __builtin_amdgcn_mfma_f32_32x32x16_bf16(kb[0], qf0, accb, 0, 0, 0);
      accb = __builtin_amdgcn_mfma_f32_32x32x16_bf16(kb[1], qf1, accb, 0, 0, 0);
      accb = __builtin_amdgcn_mfma_f32_32x32x16_bf16(kb[2], qf2, accb, 0, 0, 0);
      accb = __builtin_amdgcn_mfma_f32_32x32x16_bf16(kb[3], qf3, accb, 0, 0, 0);
      FLUSH(ktb - qt, accb);
    }
  }
}

// ---------------------------------------------------------------------------
// out (fused): block per (jc, hb) computes T for its 32 j's + 2 halo
// (8 thr each via shfl), stages in LDS, windows, stores.
// Grid 1024 = (jc 32) x (hb 32).
// ---------------------------------------------------------------------------
__global__ __launch_bounds__(256) void out_kernel(const float* __restrict__ ws,
                                                  float* __restrict__ out)
{
  __shared__ float sT[34];
  const int tid = threadIdx.x;
  const int i = blockIdx.x;
  const int hb = i & 31;
  const int jc = i >> 5;
  const int j0 = jc << 5;
  const float* TP = ws + TP2_OFF + ((size_t)hb << 16);

#define TSUM(jj_, t8_, res_)                                                  \
  {                                                                           \
    float acc_ = 0.f;                                                         \
    if ((jj_) >= 0 && (jj_) < 1024) {                                         \
      const int s_ = (jj_) + 31;                                              \
      _Pragma("unroll")                                                       \
      for (int cand = 0; cand < 2; ++cand) {                                  \
        int dt = (s_ >> 5) - cand;                                            \
        if (dt < 0 || dt > 31) continue;                                      \
        int idx = s_ - (dt << 5);                                             \
        int qmax = 31 - dt;                                                   \
        for (int qt = (t8_); qt <= qmax; qt += 8)                             \
          acc_ += TP[(((qt << 5) + dt) << 6) + idx];                          \
      }                                                                       \
    }                                                                         \
    acc_ += __shfl_down(acc_, 4, 8);                                          \
    acc_ += __shfl_down(acc_, 2, 8);                                          \
    acc_ += __shfl_down(acc_, 1, 8);                                          \
    res_ = acc_;                                                              \
  }

  {
    int jloc = tid >> 3, t8 = tid & 7;
    float r;
    TSUM(j0 + jloc - 1, t8, r);
    if (t8 == 0) sT[jloc] = r;
  }
  if (tid < 16) {
    int jx = tid >> 3, t8 = tid & 7;
    float r;
    TSUM(j0 + 31 + jx, t8, r);
    if (t8 == 0) sT[32 + jx] = r;
  }
  __syncthreads();
  if (tid < 32) {
    int j = j0 + tid;
    float cnt = (j == 0 || j == 1023) ? 2.f : 3.f;
    float v = (sT[tid] + sT[tid + 1] + sT[tid + 2]) / cnt;
    int h = hb >> 2, b = hb & 3;
    out[(((b << 10) + j) << 3) + h] = v;
  }
}

extern "C" void kernel_launch(void* const* d_in, const int* in_sizes, int n_in,
                              void* d_out, int out_size, void* d_ws, size_t ws_size,
                              hipStream_t stream)
{
  const float* x  = (const float*)d_in[0];
  const float* Wq = (const float*)d_in[1];
  const float* bq = (const float*)d_in[2];
  const float* Wk = (const float*)d_in[3];
  const float* bk = (const float*)d_in[4];
  const float* Wv = (const float*)d_in[5];
  const float* pe = (const float*)d_in[6];
  float* ws = (float*)d_ws;
  float* out = (float*)d_out;

  prep_wx_kernel<<<dim3(544), dim3(256), 0, stream>>>(x, Wq, Wk, Wv, pe, ws);
  qkgemm_kernel<<<dim3(512), dim3(256), 0, stream>>>(ws, bq, bk);
  attn_kernel<<<dim3(1024), dim3(256), 0, stream>>>(ws);
  out_kernel<<<dim3(1024), dim3(256), 0, stream>>>(ws, out);
}